// Round 2
// baseline (995.221 us; speedup 1.0000x reference)
//
#include <hip/hip_runtime.h>
#include <math.h>

#define N_NODES 10000
#define E_EDGES 160000
#define EF      170000   // E + N (self loops appended)
#define HID     128
#define HOUT    512      // HEADS*HID
#define NEG_S   0.2f

// ---------------------------------------------------------------- init / CSR
__global__ void k_zero(int* __restrict__ deg, float* __restrict__ ea_loop) {
  int i = blockIdx.x * 256 + threadIdx.x;
  if (i < N_NODES * 16) ea_loop[i] = 0.f;
  if (i < N_NODES) deg[i] = 0;
}

__global__ void k_edge_acc(const int* __restrict__ dst, const float* __restrict__ edge_attr,
                           int* __restrict__ deg, float* __restrict__ ea_sum) {
  int e = blockIdx.x * 256 + threadIdx.x;
  if (e >= E_EDGES) return;
  int v = dst[e];
  atomicAdd(&deg[v], 1);
  const float* ap = edge_attr + (size_t)e * 16;
  float* op = ea_sum + (size_t)v * 16;
#pragma unroll
  for (int j = 0; j < 16; ++j) atomicAdd(&op[j], ap[j]);
}

__global__ void k_ea_scale(float* __restrict__ ea_loop, const int* __restrict__ deg) {
  int i = blockIdx.x * 256 + threadIdx.x;
  if (i >= N_NODES * 16) return;
  float d = (float)deg[i >> 4];
  ea_loop[i] *= 1.f / fmaxf(d, 1.f);
}

__global__ __launch_bounds__(1024) void k_scan(const int* __restrict__ deg, int* __restrict__ row_ptr) {
  __shared__ int buf[1024];
  int carry = 0;
  if (threadIdx.x == 0) row_ptr[0] = 0;
  for (int base = 0; base < N_NODES; base += 1024) {
    int i = base + (int)threadIdx.x;
    int val = (i < N_NODES) ? (deg[i] + 1) : 0;
    buf[threadIdx.x] = val;
    __syncthreads();
    for (int off = 1; off < 1024; off <<= 1) {
      int t = (threadIdx.x >= (unsigned)off) ? buf[threadIdx.x - off] : 0;
      __syncthreads();
      buf[threadIdx.x] += t;
      __syncthreads();
    }
    if (i < N_NODES) row_ptr[i + 1] = carry + buf[threadIdx.x];
    carry += buf[1023];
    __syncthreads();
  }
}

__global__ void k_csr_init(const int* __restrict__ row_ptr, int* __restrict__ cursor,
                           int* __restrict__ csr_eid) {
  int v = blockIdx.x * 256 + threadIdx.x;
  if (v >= N_NODES) return;
  cursor[v] = 1;                       // slot 0 = self loop
  csr_eid[row_ptr[v]] = E_EDGES + v;
}

__global__ void k_csr_scatter(const int* __restrict__ dst, const int* __restrict__ row_ptr,
                              int* __restrict__ cursor, int* __restrict__ csr_eid) {
  int e = blockIdx.x * 256 + threadIdx.x;
  if (e >= E_EDGES) return;
  int v = dst[e];
  int pos = row_ptr[v] + atomicAdd(&cursor[v], 1);
  csr_eid[pos] = e;
}

// ------------------------------------------------------------- node embedding
__global__ __launch_bounds__(128) void k_node_emb(const float* __restrict__ x,
                                                  const float* __restrict__ W,
                                                  const float* __restrict__ b,
                                                  float* __restrict__ h) {
  __shared__ float sx[64];
  int n = blockIdx.x;
  int c = threadIdx.x;
  if (c < 64) sx[c] = x[(size_t)n * 64 + c];
  __syncthreads();
  float acc = b[c];
#pragma unroll
  for (int k = 0; k < 64; ++k) acc = fmaf(sx[k], W[k * HID + c], acc);
  h[(size_t)n * HID + c] = acc;
}

// --------------------------------------------- per-layer weight prep: C = edge_W@We, d = edge_b@We
__global__ __launch_bounds__(512) void k_prep(const float* __restrict__ edge_W,
                                              const float* __restrict__ edge_b,
                                              const float* __restrict__ We,
                                              float* __restrict__ C_all,
                                              float* __restrict__ d_all) {
  int i = blockIdx.x;   // 0..16 (16 == edge_b row)
  int l = blockIdx.y;
  int j = threadIdx.x;
  const float* wrow = (i < 16) ? (edge_W + i * HID) : edge_b;
  const float* wel = We + (size_t)l * HID * HOUT;
  float acc = 0.f;
  for (int k = 0; k < HID; ++k) acc = fmaf(wrow[k], wel[(size_t)k * HOUT + j], acc);
  if (i < 16) C_all[(size_t)l * 16 * HOUT + (size_t)i * HOUT + j] = acc;
  else        d_all[(size_t)l * HOUT + j] = acc;
}

// ------------------------------------------------------------- xl/xr GEMM
// [10000 x 128] @ [128 x 512] + bias, z picks Wl/Wr. 128x128 tile, BK=64, 8x8 microtile.
__global__ __launch_bounds__(256) void k_gemm_xlr(
    const float* __restrict__ A,
    const float* __restrict__ Wl, const float* __restrict__ bl,
    const float* __restrict__ Wr, const float* __restrict__ br,
    float* __restrict__ xl, float* __restrict__ xr) {
  const float* B = blockIdx.z ? Wr : Wl;
  const float* bias = blockIdx.z ? br : bl;
  float* out = blockIdx.z ? xr : xl;
  __shared__ float As[64][128];   // [k][m], column-swizzled
  __shared__ float Bs[64][128];   // [k][n]
  const int bm = blockIdx.x << 7;
  const int bn = blockIdx.y << 7;
  const int tid = threadIdx.x;
  const int tm = (tid >> 4) << 3;
  const int tn = (tid & 15) << 3;
  float acc[8][8] = {};
  for (int ks = 0; ks < HID; ks += 64) {
#pragma unroll
    for (int i = 0; i < 8; ++i) {           // A: 128 rows x 64 k, transpose into LDS
      int q = tid + (i << 8);
      int r = q >> 4;
      int kk = (q & 15) << 2;
      int grow = bm + r;
      float4 av = (grow < N_NODES) ? *(const float4*)(A + (size_t)grow * HID + ks + kk)
                                   : make_float4(0.f, 0.f, 0.f, 0.f);
      int f = ((kk >> 2) & 7) << 2;         // XOR swizzle kills the 16-way write conflict
      int rc = r ^ f;
      As[kk + 0][rc] = av.x; As[kk + 1][rc] = av.y;
      As[kk + 2][rc] = av.z; As[kk + 3][rc] = av.w;
    }
#pragma unroll
    for (int i = 0; i < 8; ++i) {           // B: 64 k x 128 n
      int q = tid + (i << 8);
      int r = q >> 5;
      int nn = (q & 31) << 2;
      *(float4*)(&Bs[r][nn]) = *(const float4*)(B + (size_t)(ks + r) * HOUT + bn + nn);
    }
    __syncthreads();
#pragma unroll 4
    for (int k = 0; k < 64; ++k) {
      int f = ((k >> 2) & 7) << 2;
      float a[8], b[8];
      *(float4*)(&a[0]) = *(const float4*)(&As[k][tm ^ f]);
      *(float4*)(&a[4]) = *(const float4*)(&As[k][(tm + 4) ^ f]);
      *(float4*)(&b[0]) = *(const float4*)(&Bs[k][tn]);
      *(float4*)(&b[4]) = *(const float4*)(&Bs[k][tn + 4]);
#pragma unroll
      for (int i = 0; i < 8; ++i)
#pragma unroll
        for (int j = 0; j < 8; ++j) acc[i][j] = fmaf(a[i], b[j], acc[i][j]);
    }
    __syncthreads();
  }
  float bv[8];
#pragma unroll
  for (int j = 0; j < 8; ++j) bv[j] = bias[bn + tn + j];
#pragma unroll
  for (int i = 0; i < 8; ++i) {
    int grow = bm + tm + i;
    if (grow < N_NODES) {
      float4 s0, s1;
      s0.x = acc[i][0] + bv[0]; s0.y = acc[i][1] + bv[1];
      s0.z = acc[i][2] + bv[2]; s0.w = acc[i][3] + bv[3];
      s1.x = acc[i][4] + bv[4]; s1.y = acc[i][5] + bv[5];
      s1.z = acc[i][6] + bv[6]; s1.w = acc[i][7] + bv[7];
      *(float4*)(out + (size_t)grow * HOUT + bn + tn) = s0;
      *(float4*)(out + (size_t)grow * HOUT + bn + tn + 4) = s1;
    }
  }
}

// ------------------------------------------------------------- edge logits
// wave per 64 edges; 2 passes x 256 channels; C slice resident in 64 VGPRs.
#define EEK(s, CR) \
  acc.x = fmaf(s, CR.x, acc.x); acc.y = fmaf(s, CR.y, acc.y); \
  acc.z = fmaf(s, CR.z, acc.z); acc.w = fmaf(s, CR.w, acc.w);

__global__ __launch_bounds__(256) void k_logits(
    const int* __restrict__ src, const int* __restrict__ dst,
    const float* __restrict__ edge_attr, const float* __restrict__ ea_loop,
    const int* __restrict__ deg,
    const float* __restrict__ C, const float* __restrict__ dvec,
    const float* __restrict__ att,
    const float* __restrict__ xl, const float* __restrict__ xr,
    float* __restrict__ logits) {
  int wid = threadIdx.x >> 6, lane = threadIdx.x & 63;
  int e_base = blockIdx.x * 256 + wid * 64;
  if (e_base >= EF) return;
#pragma unroll 1
  for (int pass = 0; pass < 2; ++pass) {
    int cb = pass * 256 + lane * 4;
    float4 Cr[16];
#pragma unroll
    for (int k = 0; k < 16; ++k) Cr[k] = *(const float4*)(C + k * HOUT + cb);
    float4 dv = *(const float4*)(dvec + cb);
    float4 av = *(const float4*)(att + cb);
#pragma unroll 1
    for (int ei = 0; ei < 64; ++ei) {
      int e = e_base + ei;
      if (e >= EF) break;
      int sv, tv; const float* eap; bool addD;
      if (e < E_EDGES) { sv = src[e]; tv = dst[e]; eap = edge_attr + (size_t)e * 16; addD = true; }
      else { sv = tv = e - E_EDGES; eap = ea_loop + (size_t)sv * 16; addD = deg[sv] > 0; }
      float4 e0 = *(const float4*)(eap);
      float4 e1 = *(const float4*)(eap + 4);
      float4 e2 = *(const float4*)(eap + 8);
      float4 e3 = *(const float4*)(eap + 12);
      float4 acc = addD ? dv : make_float4(0.f, 0.f, 0.f, 0.f);
      EEK(e0.x, Cr[0])  EEK(e0.y, Cr[1])  EEK(e0.z, Cr[2])  EEK(e0.w, Cr[3])
      EEK(e1.x, Cr[4])  EEK(e1.y, Cr[5])  EEK(e1.z, Cr[6])  EEK(e1.w, Cr[7])
      EEK(e2.x, Cr[8])  EEK(e2.y, Cr[9])  EEK(e2.z, Cr[10]) EEK(e2.w, Cr[11])
      EEK(e3.x, Cr[12]) EEK(e3.y, Cr[13]) EEK(e3.z, Cr[14]) EEK(e3.w, Cr[15])
      float4 xlv = *(const float4*)(xl + (size_t)sv * HOUT + cb);
      float4 xrv = *(const float4*)(xr + (size_t)tv * HOUT + cb);
      float mx = acc.x + xlv.x + xrv.x; mx = fmaxf(mx, NEG_S * mx);
      float my = acc.y + xlv.y + xrv.y; my = fmaxf(my, NEG_S * my);
      float mz = acc.z + xlv.z + xrv.z; mz = fmaxf(mz, NEG_S * mz);
      float mw = acc.w + xlv.w + xrv.w; mw = fmaxf(mw, NEG_S * mw);
      float part = mx * av.x + my * av.y + mz * av.z + mw * av.w;
#pragma unroll
      for (int off = 1; off <= 16; off <<= 1) part += __shfl_xor(part, off);
      if ((lane & 31) == 0) logits[(size_t)e * 4 + pass * 2 + (lane >> 5)] = part;
    }
  }
}

// ------------------------------------------------- softmax + aggregate per node
__global__ __launch_bounds__(256) void k_aggregate(
    const float* __restrict__ xl, const float* __restrict__ logits,
    const int* __restrict__ row_ptr, const int* __restrict__ csr_eid,
    const int* __restrict__ src, const float* __restrict__ bias,
    float* __restrict__ hout) {
  int wid = threadIdx.x >> 6, lane = threadIdx.x & 63;
  int v = blockIdx.x * 4 + wid;
  if (v >= N_NODES) return;
  int r0 = row_ptr[v], r1 = row_ptr[v + 1];
  float m0 = -1e30f, m1 = -1e30f, m2 = -1e30f, m3 = -1e30f;
  for (int i = r0 + lane; i < r1; i += 64) {
    int eid = csr_eid[i];
    float4 lg = *(const float4*)(logits + (size_t)eid * 4);
    m0 = fmaxf(m0, lg.x); m1 = fmaxf(m1, lg.y);
    m2 = fmaxf(m2, lg.z); m3 = fmaxf(m3, lg.w);
  }
#pragma unroll
  for (int off = 1; off < 64; off <<= 1) {
    m0 = fmaxf(m0, __shfl_xor(m0, off)); m1 = fmaxf(m1, __shfl_xor(m1, off));
    m2 = fmaxf(m2, __shfl_xor(m2, off)); m3 = fmaxf(m3, __shfl_xor(m3, off));
  }
  float s0 = 0.f, s1 = 0.f, s2 = 0.f, s3 = 0.f;
  for (int i = r0 + lane; i < r1; i += 64) {
    int eid = csr_eid[i];
    float4 lg = *(const float4*)(logits + (size_t)eid * 4);
    s0 += __expf(lg.x - m0); s1 += __expf(lg.y - m1);
    s2 += __expf(lg.z - m2); s3 += __expf(lg.w - m3);
  }
#pragma unroll
  for (int off = 1; off < 64; off <<= 1) {
    s0 += __shfl_xor(s0, off); s1 += __shfl_xor(s1, off);
    s2 += __shfl_xor(s2, off); s3 += __shfl_xor(s3, off);
  }
  int hl = lane >> 4;
  float mh = hl == 0 ? m0 : (hl == 1 ? m1 : (hl == 2 ? m2 : m3));
  float sh = hl == 0 ? s0 : (hl == 1 ? s1 : (hl == 2 ? s2 : s3));
  float rdh = 1.f / sh;
  float o[8] = {};
#pragma unroll 2
  for (int i = r0; i < r1; ++i) {
    int eid = csr_eid[i];
    int sv = (eid < E_EDGES) ? src[eid] : (eid - E_EDGES);
    float lg = logits[(size_t)eid * 4 + hl];
    float al = __expf(lg - mh) * rdh;
    const float4* xp = (const float4*)(xl + (size_t)sv * HOUT + lane * 8);
    float4 xa = xp[0], xb = xp[1];
    o[0] = fmaf(al, xa.x, o[0]); o[1] = fmaf(al, xa.y, o[1]);
    o[2] = fmaf(al, xa.z, o[2]); o[3] = fmaf(al, xa.w, o[3]);
    o[4] = fmaf(al, xb.x, o[4]); o[5] = fmaf(al, xb.y, o[5]);
    o[6] = fmaf(al, xb.z, o[6]); o[7] = fmaf(al, xb.w, o[7]);
  }
#pragma unroll
  for (int j = 0; j < 8; ++j) {
    float t = o[j];
    t += __shfl_xor(t, 16);
    t += __shfl_xor(t, 32);
    o[j] = t * 0.25f;
  }
  if (lane < 16) {
    int c0 = lane * 8;
    float4 w0, w1;
    w0.x = fmaxf(o[0] + bias[c0 + 0], 0.f); w0.y = fmaxf(o[1] + bias[c0 + 1], 0.f);
    w0.z = fmaxf(o[2] + bias[c0 + 2], 0.f); w0.w = fmaxf(o[3] + bias[c0 + 3], 0.f);
    w1.x = fmaxf(o[4] + bias[c0 + 4], 0.f); w1.y = fmaxf(o[5] + bias[c0 + 5], 0.f);
    w1.z = fmaxf(o[6] + bias[c0 + 6], 0.f); w1.w = fmaxf(o[7] + bias[c0 + 7], 0.f);
    *(float4*)(hout + (size_t)v * HID + c0) = w0;
    *(float4*)(hout + (size_t)v * HID + c0 + 4) = w1;
  }
}

// ---------------------------------------------------------------- launch
extern "C" void kernel_launch(void* const* d_in, const int* in_sizes, int n_in,
                              void* d_out, int out_size, void* d_ws, size_t ws_size,
                              hipStream_t stream) {
  const float* x         = (const float*)d_in[0];
  const int*   ei        = (const int*)d_in[1];
  const float* edge_attr = (const float*)d_in[2];
  const float* node_W    = (const float*)d_in[3];
  const float* node_b    = (const float*)d_in[4];
  const float* edge_W    = (const float*)d_in[5];
  const float* edge_b    = (const float*)d_in[6];
  const float* Wl        = (const float*)d_in[7];
  const float* bl        = (const float*)d_in[8];
  const float* Wr        = (const float*)d_in[9];
  const float* br        = (const float*)d_in[10];
  const float* We        = (const float*)d_in[11];
  const float* att       = (const float*)d_in[12];
  const float* bias      = (const float*)d_in[13];
  float* out = (float*)d_out;
  const int* src = ei;
  const int* dst = ei + E_EDGES;

  char* p = (char*)d_ws;
  auto alloc = [&](size_t bytes) { char* r = p; p += (bytes + 255) & ~(size_t)255; return r; };
  float* h_a     = (float*)alloc((size_t)N_NODES * HID * 4);
  float* h_b     = (float*)alloc((size_t)N_NODES * HID * 4);
  float* xl      = (float*)alloc((size_t)N_NODES * HOUT * 4);
  float* xr      = (float*)alloc((size_t)N_NODES * HOUT * 4);
  float* logits  = (float*)alloc((size_t)EF * 4 * 4);
  float* ea_loop = (float*)alloc((size_t)N_NODES * 16 * 4);
  float* C_all   = (float*)alloc((size_t)3 * 16 * HOUT * 4);
  float* d_all   = (float*)alloc((size_t)3 * HOUT * 4);
  int* deg       = (int*)alloc((size_t)N_NODES * 4);
  int* row_ptr   = (int*)alloc((size_t)(N_NODES + 1) * 4);
  int* cursor    = (int*)alloc((size_t)N_NODES * 4);
  int* csr_eid   = (int*)alloc((size_t)EF * 4);

  // preprocessing
  k_zero<<<(N_NODES * 16 + 255) / 256, 256, 0, stream>>>(deg, ea_loop);
  k_edge_acc<<<(E_EDGES + 255) / 256, 256, 0, stream>>>(dst, edge_attr, deg, ea_loop);
  k_ea_scale<<<(N_NODES * 16 + 255) / 256, 256, 0, stream>>>(ea_loop, deg);
  k_scan<<<1, 1024, 0, stream>>>(deg, row_ptr);
  k_csr_init<<<(N_NODES + 255) / 256, 256, 0, stream>>>(row_ptr, cursor, csr_eid);
  k_csr_scatter<<<(E_EDGES + 255) / 256, 256, 0, stream>>>(dst, row_ptr, cursor, csr_eid);
  k_node_emb<<<N_NODES, 128, 0, stream>>>(x, node_W, node_b, h_a);
  k_prep<<<dim3(17, 3), 512, 0, stream>>>(edge_W, edge_b, We, C_all, d_all);

  for (int l = 0; l < 3; ++l) {
    const float* hin = (l == 0) ? h_a : ((l == 1) ? h_b : h_a);
    float* hout = (l == 0) ? h_b : ((l == 1) ? h_a : out);
    k_gemm_xlr<<<dim3(79, 4, 2), 256, 0, stream>>>(
        hin, Wl + (size_t)l * HID * HOUT, bl + (size_t)l * HOUT,
        Wr + (size_t)l * HID * HOUT, br + (size_t)l * HOUT, xl, xr);
    k_logits<<<(EF + 255) / 256, 256, 0, stream>>>(
        src, dst, edge_attr, ea_loop, deg,
        C_all + (size_t)l * 16 * HOUT, d_all + (size_t)l * HOUT,
        att + (size_t)l * HOUT, xl, xr, logits);
    k_aggregate<<<2500, 256, 0, stream>>>(
        xl, logits, row_ptr, csr_eid, src, bias + (size_t)l * HID, hout);
  }
}

// Round 5
// 619.795 us; speedup vs baseline: 1.6057x; 1.6057x over previous
//
#include <hip/hip_runtime.h>
#include <math.h>

#define N_NODES 10000
#define E_EDGES 160000
#define HID     128
#define HOUT    512      // HEADS*HID
#define NEG_S   0.2f

#define RL(v_, l_) __builtin_amdgcn_readlane((v_), (l_))
__device__ __forceinline__ float rlf(float v, int l) {
  return __uint_as_float(RL(__float_as_uint(v), l));
}

// ---------------------------------------------------------------- init / CSR
__global__ void k_zero(int* __restrict__ deg) {
  int i = blockIdx.x * 256 + threadIdx.x;
  if (i < N_NODES) deg[i] = 0;
}

__global__ void k_deg(const int* __restrict__ dst, int* __restrict__ deg) {
  int e = blockIdx.x * 256 + threadIdx.x;
  if (e >= E_EDGES) return;
  atomicAdd(&deg[dst[e]], 1);
}

__global__ __launch_bounds__(1024) void k_scan(const int* __restrict__ deg, int* __restrict__ row_ptr) {
  __shared__ int buf[1024];
  int carry = 0;
  if (threadIdx.x == 0) row_ptr[0] = 0;
  for (int base = 0; base < N_NODES; base += 1024) {
    int i = base + (int)threadIdx.x;
    int val = (i < N_NODES) ? (deg[i] + 1) : 0;   // +1 slot for self loop
    buf[threadIdx.x] = val;
    __syncthreads();
    for (int off = 1; off < 1024; off <<= 1) {
      int t = (threadIdx.x >= (unsigned)off) ? buf[threadIdx.x - off] : 0;
      __syncthreads();
      buf[threadIdx.x] += t;
      __syncthreads();
    }
    if (i < N_NODES) row_ptr[i + 1] = carry + buf[threadIdx.x];
    carry += buf[1023];
    __syncthreads();
  }
}

__global__ void k_csr_init(const int* __restrict__ row_ptr, int* __restrict__ cursor,
                           int* __restrict__ csr_eid) {
  int v = blockIdx.x * 256 + threadIdx.x;
  if (v >= N_NODES) return;
  cursor[v] = 1;                       // slot 0 reserved (self loop, unused by k_fused)
  csr_eid[row_ptr[v]] = E_EDGES + v;
}

__global__ void k_csr_scatter(const int* __restrict__ dst, const int* __restrict__ row_ptr,
                              int* __restrict__ cursor, int* __restrict__ csr_eid) {
  int e = blockIdx.x * 256 + threadIdx.x;
  if (e >= E_EDGES) return;
  int v = dst[e];
  int pos = row_ptr[v] + atomicAdd(&cursor[v], 1);
  csr_eid[pos] = e;
}

// ------------------------------------------------------------- node embedding
__global__ __launch_bounds__(128) void k_node_emb(const float* __restrict__ x,
                                                  const float* __restrict__ W,
                                                  const float* __restrict__ b,
                                                  float* __restrict__ h) {
  __shared__ float sx[64];
  int n = blockIdx.x;
  int c = threadIdx.x;
  if (c < 64) sx[c] = x[(size_t)n * 64 + c];
  __syncthreads();
  float acc = b[c];
#pragma unroll
  for (int k = 0; k < 64; ++k) acc = fmaf(sx[k], W[k * HID + c], acc);
  h[(size_t)n * HID + c] = acc;
}

// --------------------------------------------- per-layer weight prep: C = edge_W@We, d = edge_b@We
__global__ __launch_bounds__(512) void k_prep(const float* __restrict__ edge_W,
                                              const float* __restrict__ edge_b,
                                              const float* __restrict__ We,
                                              float* __restrict__ C_all,
                                              float* __restrict__ d_all) {
  int i = blockIdx.x;   // 0..16 (16 == edge_b row)
  int l = blockIdx.y;
  int j = threadIdx.x;
  const float* wrow = (i < 16) ? (edge_W + i * HID) : edge_b;
  const float* wel = We + (size_t)l * HID * HOUT;
  float acc = 0.f;
  for (int k = 0; k < HID; ++k) acc = fmaf(wrow[k], wel[(size_t)k * HOUT + j], acc);
  if (i < 16) C_all[(size_t)l * 16 * HOUT + (size_t)i * HOUT + j] = acc;
  else        d_all[(size_t)l * HOUT + j] = acc;
}

// ------------------------------------------------------------- xl/xr GEMM
__global__ __launch_bounds__(256) void k_gemm_xlr(
    const float* __restrict__ A,
    const float* __restrict__ Wl, const float* __restrict__ bl,
    const float* __restrict__ Wr, const float* __restrict__ br,
    float* __restrict__ xl, float* __restrict__ xr) {
  const float* B = blockIdx.z ? Wr : Wl;
  const float* bias = blockIdx.z ? br : bl;
  float* out = blockIdx.z ? xr : xl;
  __shared__ float As[64][128];   // [k][m], column-swizzled
  __shared__ float Bs[64][128];   // [k][n]
  const int bm = blockIdx.x << 7;
  const int bn = blockIdx.y << 7;
  const int tid = threadIdx.x;
  const int tm = (tid >> 4) << 3;
  const int tn = (tid & 15) << 3;
  float acc[8][8] = {};
  for (int ks = 0; ks < HID; ks += 64) {
#pragma unroll
    for (int i = 0; i < 8; ++i) {           // A: 128 rows x 64 k, transpose into LDS
      int q = tid + (i << 8);
      int r = q >> 4;
      int kk = (q & 15) << 2;
      int grow = bm + r;
      float4 av = (grow < N_NODES) ? *(const float4*)(A + (size_t)grow * HID + ks + kk)
                                   : make_float4(0.f, 0.f, 0.f, 0.f);
      int f = ((kk >> 2) & 7) << 2;
      int rc = r ^ f;
      As[kk + 0][rc] = av.x; As[kk + 1][rc] = av.y;
      As[kk + 2][rc] = av.z; As[kk + 3][rc] = av.w;
    }
#pragma unroll
    for (int i = 0; i < 8; ++i) {           // B: 64 k x 128 n
      int q = tid + (i << 8);
      int r = q >> 5;
      int nn = (q & 31) << 2;
      *(float4*)(&Bs[r][nn]) = *(const float4*)(B + (size_t)(ks + r) * HOUT + bn + nn);
    }
    __syncthreads();
#pragma unroll 4
    for (int k = 0; k < 64; ++k) {
      int f = ((k >> 2) & 7) << 2;
      float a[8], b[8];
      *(float4*)(&a[0]) = *(const float4*)(&As[k][tm ^ f]);
      *(float4*)(&a[4]) = *(const float4*)(&As[k][(tm + 4) ^ f]);
      *(float4*)(&b[0]) = *(const float4*)(&Bs[k][tn]);
      *(float4*)(&b[4]) = *(const float4*)(&Bs[k][tn + 4]);
#pragma unroll
      for (int i = 0; i < 8; ++i)
#pragma unroll
        for (int j = 0; j < 8; ++j) acc[i][j] = fmaf(a[i], b[j], acc[i][j]);
    }
    __syncthreads();
  }
  float bv[8];
#pragma unroll
  for (int j = 0; j < 8; ++j) bv[j] = bias[bn + tn + j];
#pragma unroll
  for (int i = 0; i < 8; ++i) {
    int grow = bm + tm + i;
    if (grow < N_NODES) {
      float4 s0, s1;
      s0.x = acc[i][0] + bv[0]; s0.y = acc[i][1] + bv[1];
      s0.z = acc[i][2] + bv[2]; s0.w = acc[i][3] + bv[3];
      s1.x = acc[i][4] + bv[4]; s1.y = acc[i][5] + bv[5];
      s1.z = acc[i][6] + bv[6]; s1.w = acc[i][7] + bv[7];
      *(float4*)(out + (size_t)grow * HOUT + bn + tn) = s0;
      *(float4*)(out + (size_t)grow * HOUT + bn + tn + 4) = s1;
    }
  }
}

// ------------------------------------------------- fused logits+softmax+aggregate
// One wave per node; online softmax; C (16x512) staged in LDS per block.
__device__ __forceinline__ float edge_logit(
    float4 e0, float4 e1, float4 xa, float4 xb,
    float4 xr0, float4 xr1, float4 av0, float4 av1) {
  float t, p;
  t = e0.x + xa.x + xr0.x; t = fmaxf(t, NEG_S * t); p  = t * av0.x;
  t = e0.y + xa.y + xr0.y; t = fmaxf(t, NEG_S * t); p += t * av0.y;
  t = e0.z + xa.z + xr0.z; t = fmaxf(t, NEG_S * t); p += t * av0.z;
  t = e0.w + xa.w + xr0.w; t = fmaxf(t, NEG_S * t); p += t * av0.w;
  t = e1.x + xb.x + xr1.x; t = fmaxf(t, NEG_S * t); p += t * av1.x;
  t = e1.y + xb.y + xr1.y; t = fmaxf(t, NEG_S * t); p += t * av1.y;
  t = e1.z + xb.z + xr1.z; t = fmaxf(t, NEG_S * t); p += t * av1.z;
  t = e1.w + xb.w + xr1.w; t = fmaxf(t, NEG_S * t); p += t * av1.w;
#pragma unroll
  for (int off = 1; off <= 8; off <<= 1) p += __shfl_xor(p, off);  // per-head (16-lane) sum
  return p;
}

#define EEACC(q, c0, c1, A, B) \
  A.x = fmaf(q, c0.x, A.x); A.y = fmaf(q, c0.y, A.y); \
  A.z = fmaf(q, c0.z, A.z); A.w = fmaf(q, c0.w, A.w); \
  B.x = fmaf(q, c1.x, B.x); B.y = fmaf(q, c1.y, B.y); \
  B.z = fmaf(q, c1.z, B.z); B.w = fmaf(q, c1.w, B.w);

__global__ __launch_bounds__(512) void k_fused(
    const float* __restrict__ xl, const float* __restrict__ xr,
    const float* __restrict__ edge_attr, const int* __restrict__ src,
    const int* __restrict__ row_ptr, const int* __restrict__ csr_eid,
    const float* __restrict__ C, const float* __restrict__ dvec,
    const float* __restrict__ att, const float* __restrict__ bias,
    float* __restrict__ hout) {
  __shared__ float Cs[16 * 512];
  const int tid = threadIdx.x;
#pragma unroll
  for (int i = 0; i < 4; ++i)
    *(float4*)(&Cs[i * 2048 + tid * 4]) = *(const float4*)(C + i * 2048 + tid * 4);
  __syncthreads();

  const int wid = tid >> 6, lane = tid & 63;
  const int v = blockIdx.x * 8 + wid;
  if (v >= N_NODES) return;
  const int r0 = row_ptr[v], r1 = row_ptr[v + 1];
  const int cnt = r1 - r0 - 1;          // real incoming edges
  const int kk = lane & 15, slot = lane >> 4;
  const int cb = lane * 8;              // my 8-channel base (head = lane>>4)

  float4 av0 = *(const float4*)(att + cb),  av1 = *(const float4*)(att + cb + 4);
  float4 dv0 = *(const float4*)(dvec + cb), dv1 = *(const float4*)(dvec + cb + 4);
  float4 xr0 = *(const float4*)(xr + (size_t)v * HOUT + cb);
  float4 xr1 = *(const float4*)(xr + (size_t)v * HOUT + cb + 4);

  float o0=0,o1=0,o2=0,o3=0,o4=0,o5=0,o6=0,o7=0;
  float m = -1e30f, s = 0.f, psum = 0.f;

  for (int g = 0; g < cnt; g += 4) {
    int idx = g + slot;
    bool valL = idx < cnt;
    int pos = r0 + 1 + (valL ? idx : 0);
    int eid = csr_eid[pos];
    int sv  = src[eid];
    float ea = valL ? edge_attr[(size_t)eid * 16 + kk] : 0.f;
    psum += ea;

    int sv0 = RL(sv, 0), sv1 = RL(sv, 16), sv2 = RL(sv, 32), sv3 = RL(sv, 48);
    const float4* xp0 = (const float4*)(xl + (size_t)sv0 * HOUT + cb);
    const float4* xp1 = (const float4*)(xl + (size_t)sv1 * HOUT + cb);
    const float4* xp2 = (const float4*)(xl + (size_t)sv2 * HOUT + cb);
    const float4* xp3 = (const float4*)(xl + (size_t)sv3 * HOUT + cb);
    float4 xa0 = xp0[0], xb0 = xp0[1];
    float4 xa1 = xp1[0], xb1 = xp1[1];
    float4 xa2 = xp2[0], xb2 = xp2[1];
    float4 xa3 = xp3[0], xb3 = xp3[1];

    float4 eA0 = dv0, eB0 = dv1, eA1 = dv0, eB1 = dv1;
    float4 eA2 = dv0, eB2 = dv1, eA3 = dv0, eB3 = dv1;
    unsigned eau = __float_as_uint(ea);
#pragma unroll
    for (int k = 0; k < 16; ++k) {
      float4 c0 = *(const float4*)(&Cs[k * 512 + cb]);
      float4 c1 = *(const float4*)(&Cs[k * 512 + cb + 4]);
      float q0 = __uint_as_float(RL(eau, k));
      float q1 = __uint_as_float(RL(eau, 16 + k));
      float q2 = __uint_as_float(RL(eau, 32 + k));
      float q3 = __uint_as_float(RL(eau, 48 + k));
      EEACC(q0, c0, c1, eA0, eB0)
      EEACC(q1, c0, c1, eA1, eB1)
      EEACC(q2, c0, c1, eA2, eB2)
      EEACC(q3, c0, c1, eA3, eB3)
    }

    float lg0 = edge_logit(eA0, eB0, xa0, xb0, xr0, xr1, av0, av1);
    float lg1 = edge_logit(eA1, eB1, xa1, xb1, xr0, xr1, av0, av1);
    float lg2 = edge_logit(eA2, eB2, xa2, xb2, xr0, xr1, av0, av1);
    float lg3 = edge_logit(eA3, eB3, xa3, xb3, xr0, xr1, av0, av1);
    if (g + 1 >= cnt) lg1 = -1e30f;
    if (g + 2 >= cnt) lg2 = -1e30f;
    if (g + 3 >= cnt) lg3 = -1e30f;

    float gm = fmaxf(fmaxf(lg0, lg1), fmaxf(lg2, lg3));
    float mn = fmaxf(m, gm);
    float sc = __expf(m - mn);
    float p0 = __expf(lg0 - mn), p1 = __expf(lg1 - mn);
    float p2 = __expf(lg2 - mn), p3 = __expf(lg3 - mn);
    m = mn;
    s = s * sc + (p0 + p1) + (p2 + p3);
    o0 = o0*sc + p0*xa0.x + p1*xa1.x + p2*xa2.x + p3*xa3.x;
    o1 = o1*sc + p0*xa0.y + p1*xa1.y + p2*xa2.y + p3*xa3.y;
    o2 = o2*sc + p0*xa0.z + p1*xa1.z + p2*xa2.z + p3*xa3.z;
    o3 = o3*sc + p0*xa0.w + p1*xa1.w + p2*xa2.w + p3*xa3.w;
    o4 = o4*sc + p0*xb0.x + p1*xb1.x + p2*xb2.x + p3*xb3.x;
    o5 = o5*sc + p0*xb0.y + p1*xb1.y + p2*xb2.y + p3*xb3.y;
    o6 = o6*sc + p0*xb0.z + p1*xb1.z + p2*xb2.z + p3*xb3.z;
    o7 = o7*sc + p0*xb0.w + p1*xb1.w + p2*xb2.w + p3*xb3.w;
  }

  // ---- self loop: attr = mean of incoming edge_attr (0 if cnt==0; then also no dvec)
  psum += __shfl_xor(psum, 16);
  psum += __shfl_xor(psum, 32);
  float invd = (cnt > 0) ? (1.f / (float)cnt) : 0.f;
  float mea = psum * invd;
  float4 sA, sB;
  if (cnt > 0) { sA = dv0; sB = dv1; }
  else { sA = make_float4(0,0,0,0); sB = make_float4(0,0,0,0); }
  unsigned mu = __float_as_uint(mea);
#pragma unroll
  for (int k = 0; k < 16; ++k) {
    float4 c0 = *(const float4*)(&Cs[k * 512 + cb]);
    float4 c1 = *(const float4*)(&Cs[k * 512 + cb + 4]);
    float q = __uint_as_float(RL(mu, k));
    EEACC(q, c0, c1, sA, sB)
  }
  const float4* xsp = (const float4*)(xl + (size_t)v * HOUT + cb);
  float4 xsa = xsp[0], xsb = xsp[1];
  float lgS = edge_logit(sA, sB, xsa, xsb, xr0, xr1, av0, av1);
  {
    float mn = fmaxf(m, lgS);
    float sc = __expf(m - mn);
    float pS = __expf(lgS - mn);
    m = mn;
    s = s * sc + pS;
    o0 = o0*sc + pS*xsa.x; o1 = o1*sc + pS*xsa.y;
    o2 = o2*sc + pS*xsa.z; o3 = o3*sc + pS*xsa.w;
    o4 = o4*sc + pS*xsb.x; o5 = o5*sc + pS*xsb.y;
    o6 = o6*sc + pS*xsb.z; o7 = o7*sc + pS*xsb.w;
  }

  // ---- normalize, head-mean, bias, relu, store
  float inv_s = 1.f / s;
  float r[8] = {o0*inv_s, o1*inv_s, o2*inv_s, o3*inv_s,
                o4*inv_s, o5*inv_s, o6*inv_s, o7*inv_s};
#pragma unroll
  for (int j = 0; j < 8; ++j) {
    float t = r[j];
    t += __shfl_xor(t, 16);
    t += __shfl_xor(t, 32);
    r[j] = t * 0.25f;
  }
  if (lane < 16) {
    float4 w0, w1;
    w0.x = fmaxf(r[0] + bias[cb + 0], 0.f); w0.y = fmaxf(r[1] + bias[cb + 1], 0.f);
    w0.z = fmaxf(r[2] + bias[cb + 2], 0.f); w0.w = fmaxf(r[3] + bias[cb + 3], 0.f);
    w1.x = fmaxf(r[4] + bias[cb + 4], 0.f); w1.y = fmaxf(r[5] + bias[cb + 5], 0.f);
    w1.z = fmaxf(r[6] + bias[cb + 6], 0.f); w1.w = fmaxf(r[7] + bias[cb + 7], 0.f);
    *(float4*)(hout + (size_t)v * HID + cb) = w0;
    *(float4*)(hout + (size_t)v * HID + cb + 4) = w1;
  }
}

// ---------------------------------------------------------------- launch
extern "C" void kernel_launch(void* const* d_in, const int* in_sizes, int n_in,
                              void* d_out, int out_size, void* d_ws, size_t ws_size,
                              hipStream_t stream) {
  const float* x         = (const float*)d_in[0];
  const int*   ei        = (const int*)d_in[1];
  const float* edge_attr = (const float*)d_in[2];
  const float* node_W    = (const float*)d_in[3];
  const float* node_b    = (const float*)d_in[4];
  const float* edge_W    = (const float*)d_in[5];
  const float* edge_b    = (const float*)d_in[6];
  const float* Wl        = (const float*)d_in[7];
  const float* bl        = (const float*)d_in[8];
  const float* Wr        = (const float*)d_in[9];
  const float* br        = (const float*)d_in[10];
  const float* We        = (const float*)d_in[11];
  const float* att       = (const float*)d_in[12];
  const float* bias      = (const float*)d_in[13];
  float* out = (float*)d_out;
  const int* src = ei;
  const int* dst = ei + E_EDGES;

  char* p = (char*)d_ws;
  auto alloc = [&](size_t bytes) { char* r = p; p += (bytes + 255) & ~(size_t)255; return r; };
  float* h_a     = (float*)alloc((size_t)N_NODES * HID * 4);
  float* h_b     = (float*)alloc((size_t)N_NODES * HID * 4);
  float* xl      = (float*)alloc((size_t)N_NODES * HOUT * 4);
  float* xr      = (float*)alloc((size_t)N_NODES * HOUT * 4);
  float* C_all   = (float*)alloc((size_t)3 * 16 * HOUT * 4);
  float* d_all   = (float*)alloc((size_t)3 * HOUT * 4);
  int* deg       = (int*)alloc((size_t)N_NODES * 4);
  int* row_ptr   = (int*)alloc((size_t)(N_NODES + 1) * 4);
  int* cursor    = (int*)alloc((size_t)N_NODES * 4);
  int* csr_eid   = (int*)alloc((size_t)(E_EDGES + N_NODES) * 4);

  // preprocessing
  k_zero<<<(N_NODES + 255) / 256, 256, 0, stream>>>(deg);
  k_deg<<<(E_EDGES + 255) / 256, 256, 0, stream>>>(dst, deg);
  k_scan<<<1, 1024, 0, stream>>>(deg, row_ptr);
  k_csr_init<<<(N_NODES + 255) / 256, 256, 0, stream>>>(row_ptr, cursor, csr_eid);
  k_csr_scatter<<<(E_EDGES + 255) / 256, 256, 0, stream>>>(dst, row_ptr, cursor, csr_eid);
  k_node_emb<<<N_NODES, 128, 0, stream>>>(x, node_W, node_b, h_a);
  k_prep<<<dim3(17, 3), 512, 0, stream>>>(edge_W, edge_b, We, C_all, d_all);

  for (int l = 0; l < 3; ++l) {
    const float* hin = (l == 0) ? h_a : ((l == 1) ? h_b : h_a);
    float* hout = (l == 0) ? h_b : ((l == 1) ? h_a : out);
    k_gemm_xlr<<<dim3(79, 4, 2), 256, 0, stream>>>(
        hin, Wl + (size_t)l * HID * HOUT, bl + (size_t)l * HOUT,
        Wr + (size_t)l * HID * HOUT, br + (size_t)l * HOUT, xl, xr);
    k_fused<<<(N_NODES + 7) / 8, 512, 0, stream>>>(
        xl, xr, edge_attr, src, row_ptr, csr_eid,
        C_all + (size_t)l * 16 * HOUT, d_all + (size_t)l * HOUT,
        att + (size_t)l * HOUT, bias + (size_t)l * HID, hout);
  }
}